// Round 8
// baseline (149.174 us; speedup 1.0000x reference)
//
#include <hip/hip_runtime.h>
#include <hip/hip_bf16.h>

typedef __attribute__((ext_vector_type(8))) short short8;
typedef __attribute__((ext_vector_type(4))) short short4v;
typedef __attribute__((ext_vector_type(4))) float f32x4;
typedef __attribute__((ext_vector_type(16))) float f32x16;
typedef __attribute__((ext_vector_type(4))) int i32x4;
typedef __attribute__((ext_vector_type(16))) int i32x16;
typedef __attribute__((ext_vector_type(2))) unsigned u32x2;

namespace {
constexpr int NSEQ = 2048;
constexpr int NHEAD = 16;
constexpr int NDIM = 128;
constexpr int VTP = 72;              // V^T pair row stride (shorts); 144B = 9*16B (odd) -> conflict-free column b128 reads
constexpr int ROWI = NHEAD * NDIM;   // 2048 ints per seq row
}

// int in [-128,127] -> bf16 bits, exact
__device__ __forceinline__ short i2bf(int v) {
    union { float f; unsigned u; } x; x.f = (float)v;
    return (short)(x.u >> 16);
}
// 4 int32 (int8 values) -> 1 dword of 4 packed i8
__device__ __forceinline__ unsigned pack8(const int4 &a) {
    return (unsigned)(a.x & 255) | ((unsigned)(a.y & 255) << 8) |
           ((unsigned)(a.z & 255) << 16) | ((unsigned)a.w << 24);
}
// permlane32_swap: a' = [a_lo32 | b_lo32], b' = [a_hi32 | b_hi32]
__device__ __forceinline__ void plswap(unsigned &a, unsigned &b) {
#if __has_builtin(__builtin_amdgcn_permlane32_swap)
    u32x2 r = __builtin_amdgcn_permlane32_swap(a, b, false, false);
    a = r[0]; b = r[1];
#else
    asm volatile("v_permlane32_swap_b32 %0, %1" : "+v"(a), "+v"(b));  // a,b always distinct values here
#endif
}
// 8 probabilities (kv = (r&3)+8*(r>>2)+4*h5 within 16) -> bf16 B-frag words for one 16-kv chunk
__device__ __forceinline__ void p_to_frag(const float *p, unsigned *pw) {
    unsigned A0, A1, B0, B1;
    asm("v_cvt_pk_bf16_f32 %0, %1, %2" : "=v"(A0) : "v"(p[0]), "v"(p[1]));
    asm("v_cvt_pk_bf16_f32 %0, %1, %2" : "=v"(A1) : "v"(p[2]), "v"(p[3]));
    asm("v_cvt_pk_bf16_f32 %0, %1, %2" : "=v"(B0) : "v"(p[4]), "v"(p[5]));
    asm("v_cvt_pk_bf16_f32 %0, %1, %2" : "=v"(B1) : "v"(p[6]), "v"(p[7]));
    plswap(A0, B0);
    plswap(A1, B1);
    pw[0] = A0; pw[1] = A1; pw[2] = B0; pw[3] = B1;
}

__global__ __launch_bounds__(256, 2)
void qattn_fwd(const int* __restrict__ qq, const int* __restrict__ kq,
               const int* __restrict__ vq, const float* __restrict__ qsc,
               const float* __restrict__ ksc, const float* __restrict__ vsc,
               float* __restrict__ out)
{
    // 512 blocks. bh = id&31 (same bh -> same XCD since 32%8==0).
    // idx pairing: CU gets idx and idx+8 -> jq pair (15-k, k): constant work per CU.
    const int id = blockIdx.x;
    const int bh = id & 31;
    const int idx = id >> 5;                       // 0..15
    const int jq = (idx < 8) ? (15 - idx) : (idx - 8);
    const int b = bh >> 4, h = bh & 15;
    const int t = threadIdx.x;
    const int lane = t & 63;
    const int w = t >> 6;                          // wave 0..3
    const int l31 = lane & 31;
    const int h5 = lane >> 5;

    __shared__ __align__(16) unsigned k_lds[2][2][32 * 32]; // 16 KB: [dbuf][tile][row*32+dw], packed i8, XOR-swz
    __shared__ __align__(16) short vt_lds[2][NDIM * VTP];   // 36 KB: [dbuf] V^T pair [d][64 kv]

    const float sc2 = qsc[h] * ksc[h] * (0.08838834764831845f * 1.4426950408889634f); // /sqrt(D)*log2e
    const float vscale = vsc[h];

    const int q0 = jq * 128 + w * 32;              // this wave's 32 q rows
    const int q_hi = q0 + 31;
    const int npairs = (jq + 1) * 2;               // 64-kv pair phases staged for this block

    const int* kB = kq + (size_t)b * NSEQ * ROWI + h * NDIM;
    const int* vB = vq + (size_t)b * NSEQ * ROWI + h * NDIM;

    // ---- Q fragments (B-operand of 32x32x32_i8): lane owns q col = q0+l31,
    //      chunk c covers d = c*32 + h5*16 + [0,16), packed 4 dwords ----
    i32x4 qf[4];
    {
        const int* qp = qq + (size_t)(b * NSEQ + q0 + l31) * ROWI + h * NDIM + h5 * 16;
        #pragma unroll
        for (int c = 0; c < 4; ++c) {
            int4 a0 = *(const int4*)(qp + c * 32);
            int4 a1 = *(const int4*)(qp + c * 32 + 4);
            int4 a2 = *(const int4*)(qp + c * 32 + 8);
            int4 a3 = *(const int4*)(qp + c * 32 + 12);
            i32x4 f = { (int)pack8(a0), (int)pack8(a1), (int)pack8(a2), (int)pack8(a3) };
            qf[c] = f;
        }
    }

    f32x16 o_acc[4];                   // O^T: o_acc[dt][r] = O[d = dt*32 + (r&3)+8*(r>>2)+4*h5][q = q0+l31]
    #pragma unroll
    for (int dt = 0; dt < 4; ++dt)
        #pragma unroll
        for (int r = 0; r < 16; ++r) o_acc[dt][r] = 0.f;
    float m_run = -1e30f, l_run = 0.f; // per-lane: lane owns one q row

    // ---- staging decomposition (256 threads, per 64-kv pair) ----
    const int kr  = t >> 3;            // K: row 0..31 (per tile)
    const int db  = t & 7;             // K: dword-group (16 bytes of d)
    const int kvh = t & 7;             // V: kv rows kvh*4..+3 (per tile)
    const int dgv = t >> 3;            // V: d cols dgv*4..+3
    int4 ka[8], va[8];                 // in-flight pair staging (T14)

    auto ISSUE = [&](int u) {
        const int kv = u * 64;
        #pragma unroll
        for (int tile = 0; tile < 2; ++tile) {
            const int* kp = kB + (kv + tile * 32 + kr) * ROWI + db * 16;
            ka[tile * 4 + 0] = *(const int4*)(kp + 0);
            ka[tile * 4 + 1] = *(const int4*)(kp + 4);
            ka[tile * 4 + 2] = *(const int4*)(kp + 8);
            ka[tile * 4 + 3] = *(const int4*)(kp + 12);
            const int* vp = vB + (kv + tile * 32 + kvh * 4) * ROWI + dgv * 4;
            va[tile * 4 + 0] = *(const int4*)vp;
            va[tile * 4 + 1] = *(const int4*)(vp + ROWI);
            va[tile * 4 + 2] = *(const int4*)(vp + 2 * ROWI);
            va[tile * 4 + 3] = *(const int4*)(vp + 3 * ROWI);
        }
    };
    auto WRITE = [&](int u) {
        const int buf = u & 1;
        const int kidx = kr * 32 + ((db * 4) ^ ((kr & 7) << 2));   // 16B-group XOR swizzle
        #pragma unroll
        for (int tile = 0; tile < 2; ++tile) {
            i32x4 kk = { (int)pack8(ka[tile * 4 + 0]), (int)pack8(ka[tile * 4 + 1]),
                         (int)pack8(ka[tile * 4 + 2]), (int)pack8(ka[tile * 4 + 3]) };
            *(i32x4*)&k_lds[buf][tile][kidx] = kk;
            short4v c0 = { i2bf(va[tile*4+0].x), i2bf(va[tile*4+1].x), i2bf(va[tile*4+2].x), i2bf(va[tile*4+3].x) };
            short4v c1 = { i2bf(va[tile*4+0].y), i2bf(va[tile*4+1].y), i2bf(va[tile*4+2].y), i2bf(va[tile*4+3].y) };
            short4v c2 = { i2bf(va[tile*4+0].z), i2bf(va[tile*4+1].z), i2bf(va[tile*4+2].z), i2bf(va[tile*4+3].z) };
            short4v c3 = { i2bf(va[tile*4+0].w), i2bf(va[tile*4+1].w), i2bf(va[tile*4+2].w), i2bf(va[tile*4+3].w) };
            short* vb = &vt_lds[buf][(dgv * 4) * VTP + tile * 32 + kvh * 4];
            *(short4v*)(vb + 0 * VTP) = c0;
            *(short4v*)(vb + 1 * VTP) = c1;
            *(short4v*)(vb + 2 * VTP) = c2;
            *(short4v*)(vb + 3 * VTP) = c3;
        }
    };

    ISSUE(0);
    for (int u = 0; u < npairs; ++u) {
        WRITE(u);
        if (u + 1 < npairs) ISSUE(u + 1);
        __syncthreads();

        const int kvA = u * 64;
        const int kvB = kvA + 32;
        if (kvA > q_hi) continue;          // wave-uniform causal skip (barrier already passed)
        const bool doB = (kvB <= q_hi);    // wave-uniform
        const int buf = u & 1;
        const int swd = (l31 & 7) << 2;

        // ---- QK^T (swapped, int8 exact): C = S^T, col = l31 = q, kv = (r&3)+8*(r>>2)+4*h5 ----
        i32x16 sA, sB;
        #pragma unroll
        for (int r = 0; r < 16; ++r) { sA[r] = 0; sB[r] = 0; }
        i32x4 kbA[4], kbB[4];
        #pragma unroll
        for (int c = 0; c < 4; ++c)
            kbA[c] = *(const i32x4*)&k_lds[buf][0][l31 * 32 + ((c * 8 + h5 * 4) ^ swd)];
        if (doB) {
            #pragma unroll
            for (int c = 0; c < 4; ++c)
                kbB[c] = *(const i32x4*)&k_lds[buf][1][l31 * 32 + ((c * 8 + h5 * 4) ^ swd)];
        }
        __builtin_amdgcn_s_setprio(1);
        #pragma unroll
        for (int c = 0; c < 4; ++c)
            sA = __builtin_amdgcn_mfma_i32_32x32x32_i8(kbA[c], qf[c], sA, 0, 0, 0);
        if (doB) {
            #pragma unroll
            for (int c = 0; c < 4; ++c)
                sB = __builtin_amdgcn_mfma_i32_32x32x32_i8(kbB[c], qf[c], sB, 0, 0, 0);
        }
        __builtin_amdgcn_s_setprio(0);

        // ---- masks (diag tile only; raw-score f32 domain) ----
        float svA[16], svB[16];
        if (kvA == q0) {                       // A diag (then doB=false)
            #pragma unroll
            for (int r = 0; r < 16; ++r) {
                const int kvr = (r & 3) + 8 * (r >> 2) + 4 * h5;
                svA[r] = (kvr <= l31) ? (float)sA[r] : -1e30f;
            }
        } else {
            #pragma unroll
            for (int r = 0; r < 16; ++r) svA[r] = (float)sA[r];
        }
        if (doB) {
            if (kvB == q0) {                   // B diag
                #pragma unroll
                for (int r = 0; r < 16; ++r) {
                    const int kvr = (r & 3) + 8 * (r >> 2) + 4 * h5;
                    svB[r] = (kvr <= l31) ? (float)sB[r] : -1e30f;
                }
            } else {
                #pragma unroll
                for (int r = 0; r < 16; ++r) svB[r] = (float)sB[r];
            }
        }

        // ---- merged in-register online softmax (sc2 > 0 so max commutes) ----
        float rmax = svA[0];
        #pragma unroll
        for (int r = 1; r < 16; ++r) rmax = fmaxf(rmax, svA[r]);
        if (doB) {
            #pragma unroll
            for (int r = 0; r < 16; ++r) rmax = fmaxf(rmax, svB[r]);
        }
        rmax = fmaxf(rmax, __shfl_xor(rmax, 32, 64));      // cross-half max
        const bool need = (rmax - m_run) * sc2 > 8.0f;     // T13 defer-rescale
        if (__any((int)need)) {
            const float mn = fmaxf(m_run, rmax);
            const float sf = exp2f((m_run - mn) * sc2);
            m_run = mn;
            l_run *= sf;
            #pragma unroll
            for (int dt = 0; dt < 4; ++dt)
                #pragma unroll
                for (int r = 0; r < 16; ++r) o_acc[dt][r] *= sf;
        }
        const float nm = m_run * sc2;
        float pA[16], pB[16];
        float ps = 0.f;
        #pragma unroll
        for (int r = 0; r < 16; ++r) {
            pA[r] = exp2f(__builtin_fmaf(svA[r], sc2, -nm));
            ps += pA[r];
        }
        if (doB) {
            #pragma unroll
            for (int r = 0; r < 16; ++r) {
                pB[r] = exp2f(__builtin_fmaf(svB[r], sc2, -nm));
                ps += pB[r];
            }
        }
        ps += __shfl_xor(ps, 32, 64);                      // cross-half sum
        l_run += ps;

        // ---- P -> bf16 B-frags in-register (T12) ----
        union { unsigned u4[4]; short8 v; } pfA0, pfA1, pfB0, pfB1;
        p_to_frag(&pA[0], pfA0.u4);
        p_to_frag(&pA[8], pfA1.u4);
        if (doB) {
            p_to_frag(&pB[0], pfB0.u4);
            p_to_frag(&pB[8], pfB1.u4);
        }

        // ---- PV (swapped): O^T[d][q] += V^T[d][kv] * P^T[kv][q] ----
        __builtin_amdgcn_s_setprio(1);
        #pragma unroll
        for (int dt = 0; dt < 4; ++dt) {
            const int drow = dt * 32 + l31;
            const short8 vbA0 = *(const short8*)&vt_lds[buf][drow * VTP + h5 * 8];
            o_acc[dt] = __builtin_amdgcn_mfma_f32_32x32x16_bf16(vbA0, pfA0.v, o_acc[dt], 0, 0, 0);
            const short8 vbA1 = *(const short8*)&vt_lds[buf][drow * VTP + 16 + h5 * 8];
            o_acc[dt] = __builtin_amdgcn_mfma_f32_32x32x16_bf16(vbA1, pfA1.v, o_acc[dt], 0, 0, 0);
            if (doB) {
                const short8 vbB0 = *(const short8*)&vt_lds[buf][drow * VTP + 32 + h5 * 8];
                o_acc[dt] = __builtin_amdgcn_mfma_f32_32x32x16_bf16(vbB0, pfB0.v, o_acc[dt], 0, 0, 0);
                const short8 vbB1 = *(const short8*)&vt_lds[buf][drow * VTP + 48 + h5 * 8];
                o_acc[dt] = __builtin_amdgcn_mfma_f32_32x32x16_bf16(vbB1, pfB1.v, o_acc[dt], 0, 0, 0);
            }
        }
        __builtin_amdgcn_s_setprio(0);
    }

    // ---- epilogue: O^T -> out, per-lane scalar normalize ----
    {
        const float sr = vscale / l_run;
        float* op = out + (size_t)(b * NSEQ + q0 + l31) * ROWI + h * NDIM;
        #pragma unroll
        for (int dt = 0; dt < 4; ++dt) {
            #pragma unroll
            for (int gq = 0; gq < 4; ++gq) {
                f32x4 v = { o_acc[dt][gq * 4 + 0] * sr, o_acc[dt][gq * 4 + 1] * sr,
                            o_acc[dt][gq * 4 + 2] * sr, o_acc[dt][gq * 4 + 3] * sr };
                *(f32x4*)(op + dt * 32 + 8 * gq + 4 * h5) = v;
            }
        }
    }
}

extern "C" void kernel_launch(void* const* d_in, const int* in_sizes, int n_in,
                              void* d_out, int out_size, void* d_ws, size_t ws_size,
                              hipStream_t stream) {
    const int* qq = (const int*)d_in[0];
    const int* kq = (const int*)d_in[1];
    const int* vq = (const int*)d_in[2];
    const float* qsc = (const float*)d_in[3];
    const float* ksc = (const float*)d_in[4];
    const float* vsc = (const float*)d_in[5];
    float* out = (float*)d_out;
    (void)d_ws; (void)ws_size; (void)in_sizes; (void)n_in; (void)out_size;

    qattn_fwd<<<dim3(512), dim3(256), 0, stream>>>(qq, kq, vq, qsc, ksc, vsc, out);
}